// Round 1
// baseline (1101.916 us; speedup 1.0000x reference)
//
#include <hip/hip_runtime.h>
#include <math.h>

#define IMG_H 3072
#define IMG_W 4096
#define Hh 1536
#define Wh 2048
#define S (Hh*Wh)   // 3,145,728 per-plane pixels

__device__ __forceinline__ float clamp01(float v){ return fminf(fmaxf(v, 0.0f), 1.0f); }

// jnp.interp over knots (0,0),(0.25,0.5),(1,1) then black-level
__device__ __forceinline__ float decompand_black(float v){
  float y = (v <= 0.25f) ? (2.0f*v) : fmaf(v - 0.25f, 0.5f/0.75f, 0.5f);
  y = clamp01(y);
  return clamp01((y - 0.0625f) * (1.0f/0.9375f));
}

// ---- K1: decompand + split into 4 RGGB planes ----
__global__ __launch_bounds__(256) void k_split(const float* __restrict__ x, float* __restrict__ P){
  int idx = blockIdx.x*256 + threadIdx.x;
  int i = idx >> 11, j = idx & 2047;
  const float* r0 = x + (2*i)*IMG_W + 2*j;
  const float* r1 = r0 + IMG_W;
  float2 a = *(const float2*)r0;
  float2 b = *(const float2*)r1;
  P[idx]       = decompand_black(a.x);
  P[S + idx]   = decompand_black(a.y);
  P[2*S + idx] = decompand_black(b.x);
  P[3*S + idx] = decompand_black(b.y);
}

// ---- K2: guided filter pass 1 (r=2, eps=100): per-pixel 5x5 truncated box ----
__global__ __launch_bounds__(256) void k_gf1(const float* __restrict__ pl,
                                             float* __restrict__ A, float* __restrict__ B){
  int idx = blockIdx.x*256 + threadIdx.x;
  int i = idx >> 11, j = idx & 2047;
  float s = 0.f, s2 = 0.f, cnt;
  if (i >= 2 && i < Hh-2 && j >= 2 && j < Wh-2){
    #pragma unroll
    for (int dy=-2; dy<=2; ++dy){
      const float* row = pl + (i+dy)*Wh + j;
      #pragma unroll
      for (int dx=-2; dx<=2; ++dx){ float v = row[dx]; s += v; s2 = fmaf(v, v, s2); }
    }
    cnt = 25.f;
  } else {
    int r0 = max(i-2,0), r1 = min(i+2,Hh-1);
    int c0 = max(j-2,0), c1 = min(j+2,Wh-1);
    for (int r=r0; r<=r1; ++r){
      const float* row = pl + r*Wh;
      for (int c=c0; c<=c1; ++c){ float v = row[c]; s += v; s2 = fmaf(v, v, s2); }
    }
    cnt = (float)((r1-r0+1)*(c1-c0+1));
  }
  float inv = 1.0f/cnt;
  float m   = s*inv;
  float var = fmaf(-m, m, s2*inv);
  float a   = var/(var + 100.0f);
  A[idx] = a;
  B[idx] = m*(1.0f - a);
}

// ---- K3: guided filter pass 2: box(a), box(b) -> D = boxa*I + boxb; plane-sum reduce ----
__global__ __launch_bounds__(256) void k_gf2(const float* __restrict__ pl,
                                             const float* __restrict__ A, const float* __restrict__ B,
                                             float* __restrict__ D, float* __restrict__ sum_out){
  int idx = blockIdx.x*256 + threadIdx.x;
  int i = idx >> 11, j = idx & 2047;
  float sa = 0.f, sb = 0.f, cnt;
  if (i >= 2 && i < Hh-2 && j >= 2 && j < Wh-2){
    #pragma unroll
    for (int dy=-2; dy<=2; ++dy){
      int base = (i+dy)*Wh + j;
      #pragma unroll
      for (int dx=-2; dx<=2; ++dx){ sa += A[base+dx]; sb += B[base+dx]; }
    }
    cnt = 25.f;
  } else {
    int r0 = max(i-2,0), r1 = min(i+2,Hh-1);
    int c0 = max(j-2,0), c1 = min(j+2,Wh-1);
    for (int r=r0; r<=r1; ++r){
      int base = r*Wh;
      for (int c=c0; c<=c1; ++c){ sa += A[base+c]; sb += B[base+c]; }
    }
    cnt = (float)((r1-r0+1)*(c1-c0+1));
  }
  float inv = 1.0f/cnt;
  float d = fmaf(sa*inv, pl[idx], sb*inv);
  D[idx] = d;
  // block reduction -> one atomic per block (AWB mean over denoised plane, pre-clip)
  __shared__ float red[256];
  red[threadIdx.x] = d;
  __syncthreads();
  #pragma unroll
  for (int off=128; off>0; off>>=1){
    if (threadIdx.x < off) red[threadIdx.x] += red[threadIdx.x+off];
    __syncthreads();
  }
  if (threadIdx.x == 0) atomicAdd(sum_out, red[0]);
}

// ---- K4: AWB gains ----
__global__ void k_gains(const float* __restrict__ sums, float* __restrict__ gains){
  if (threadIdx.x == 0 && blockIdx.x == 0){
    const float inv = 1.0f/(float)S;
    float rm = sums[0]*inv, g1 = sums[1]*inv, g2 = sums[2]*inv, bm = sums[3]*inv;
    float gm = 0.5f*(g1+g2);
    gains[0] = fminf(gm/(rm + 1e-8f), 4.0f);
    gains[1] = fminf(gm/(bm + 1e-8f), 4.0f);
  }
}

// ---- K5: rebuild gained, clipped mosaic ----
__global__ __launch_bounds__(256) void k_mosaic(const float* __restrict__ D, const float* __restrict__ gains,
                                                float* __restrict__ M){
  int idx = blockIdx.x*256 + threadIdx.x;
  int i = idx >> 11, j = idx & 2047;
  float gr = gains[0], gb = gains[1];
  float2 t0 = make_float2(clamp01(D[idx]*gr),  clamp01(D[S+idx]));
  float2 t1 = make_float2(clamp01(D[2*S+idx]), clamp01(D[3*S+idx]*gb));
  *(float2*)(M + (2*i)*IMG_W   + 2*j) = t0;
  *(float2*)(M + (2*i+1)*IMG_W + 2*j) = t1;
}

// ---- shared demosaic helpers (zero-padded 'SAME' 3x3 convs, RGGB) ----
__device__ __forceinline__ void load_m44(const float* __restrict__ M, int i, int j, float m[4][4]){
  int y0 = 2*i - 1, x0 = 2*j - 1;
  #pragma unroll
  for (int a=0; a<4; ++a){
    int yy = y0 + a;
    bool yok = ((unsigned)yy < (unsigned)IMG_H);
    #pragma unroll
    for (int b=0; b<4; ++b){
      int xx = x0 + b;
      m[a][b] = (yok && ((unsigned)xx < (unsigned)IMG_W)) ? M[yy*IMG_W + xx] : 0.0f;
    }
  }
}

__device__ __forceinline__ void demosaic_ccm(const float m[4][4], const float* __restrict__ C,
                                             float R[2][2], float G[2][2], float Bv[2][2]){
  float r[2][2], g[2][2], b[2][2];
  // (0,0) = R site
  r[0][0] = m[1][1];
  g[0][0] = 0.25f*(m[0][1]+m[2][1]+m[1][0]+m[1][2]);
  b[0][0] = 0.25f*(m[0][0]+m[0][2]+m[2][0]+m[2][2]);
  // (0,1) = G site (R row)
  r[0][1] = 0.5f*(m[1][1]+m[1][3]);
  g[0][1] = m[1][2];
  b[0][1] = 0.5f*(m[0][2]+m[2][2]);
  // (1,0) = G site (B row)
  r[1][0] = 0.5f*(m[1][1]+m[3][1]);
  g[1][0] = m[2][1];
  b[1][0] = 0.5f*(m[2][0]+m[2][2]);
  // (1,1) = B site
  r[1][1] = 0.25f*(m[1][1]+m[1][3]+m[3][1]+m[3][3]);
  g[1][1] = 0.25f*(m[1][2]+m[3][2]+m[2][1]+m[2][3]);
  b[1][1] = m[2][2];
  #pragma unroll
  for (int a=0; a<2; ++a){
    #pragma unroll
    for (int c=0; c<2; ++c){
      R[a][c]  = clamp01(fmaf(C[2], b[a][c], fmaf(C[1], g[a][c], C[0]*r[a][c])));
      G[a][c]  = clamp01(fmaf(C[5], b[a][c], fmaf(C[4], g[a][c], C[3]*r[a][c])));
      Bv[a][c] = clamp01(fmaf(C[8], b[a][c], fmaf(C[7], g[a][c], C[6]*r[a][c])));
    }
  }
}

// ---- K6: half-res luma Ys (2x2 mean of CCM'd luma) ----
__global__ __launch_bounds__(256) void k_ys(const float* __restrict__ M, const float* __restrict__ C,
                                            float* __restrict__ Ys){
  int idx = blockIdx.x*256 + threadIdx.x;
  int i = idx >> 11, j = idx & 2047;
  float m[4][4]; load_m44(M, i, j, m);
  float R[2][2], G[2][2], Bv[2][2];
  demosaic_ccm(m, C, R, G, Bv);
  float y = 0.f;
  #pragma unroll
  for (int a=0; a<2; ++a)
    #pragma unroll
    for (int c=0; c<2; ++c)
      y += 0.299f*R[a][c] + 0.587f*G[a][c] + 0.114f*Bv[a][c];
  Ys[idx] = 0.25f*y;
}

// ---- K7a: horizontal 17-tap sums of Ys and Ys^2 ----
__global__ __launch_bounds__(256) void k_hbox_sq(const float* __restrict__ in,
                                                 float* __restrict__ o1, float* __restrict__ o2){
  int idx = blockIdx.x*256 + threadIdx.x;
  int i = idx >> 11, j = idx & 2047;
  const float* row = in + (i<<11);
  float s = 0.f, s2 = 0.f;
  if (j >= 8 && j < Wh-8){
    #pragma unroll
    for (int d=-8; d<=8; ++d){ float v = row[j+d]; s += v; s2 = fmaf(v, v, s2); }
  } else {
    int c0 = max(j-8,0), c1 = min(j+8,Wh-1);
    for (int c=c0; c<=c1; ++c){ float v = row[c]; s += v; s2 = fmaf(v, v, s2); }
  }
  o1[idx] = s; o2[idx] = s2;
}

// ---- K7b: vertical 17-tap + a,b (eps=1e-3) ----
__global__ __launch_bounds__(256) void k_vbox_ab(const float* __restrict__ h1, const float* __restrict__ h2,
                                                 float* __restrict__ A, float* __restrict__ B){
  int idx = blockIdx.x*256 + threadIdx.x;
  int i = idx >> 11, j = idx & 2047;
  float s1 = 0.f, s2 = 0.f; int ry;
  if (i >= 8 && i < Hh-8){
    #pragma unroll
    for (int d=-8; d<=8; ++d){ int o = ((i+d)<<11) + j; s1 += h1[o]; s2 += h2[o]; }
    ry = 17;
  } else {
    int r0 = max(i-8,0), r1 = min(i+8,Hh-1);
    for (int r=r0; r<=r1; ++r){ int o = (r<<11) + j; s1 += h1[o]; s2 += h2[o]; }
    ry = r1-r0+1;
  }
  int cw = min(j+8, Wh-1) - max(j-8, 0) + 1;
  float inv = 1.0f/(float)(ry*cw);
  float m   = s1*inv;
  float var = fmaf(-m, m, s2*inv);
  float a   = var/(var + 1e-3f);
  A[idx] = a;
  B[idx] = m*(1.0f - a);
}

// ---- K7c: horizontal 17-tap sums of a and b ----
__global__ __launch_bounds__(256) void k_hbox2(const float* __restrict__ i1, const float* __restrict__ i2,
                                               float* __restrict__ o1, float* __restrict__ o2){
  int idx = blockIdx.x*256 + threadIdx.x;
  int i = idx >> 11, j = idx & 2047;
  int ro = i << 11;
  float s1 = 0.f, s2 = 0.f;
  if (j >= 8 && j < Wh-8){
    #pragma unroll
    for (int d=-8; d<=8; ++d){ s1 += i1[ro+j+d]; s2 += i2[ro+j+d]; }
  } else {
    int c0 = max(j-8,0), c1 = min(j+8,Wh-1);
    for (int c=c0; c<=c1; ++c){ s1 += i1[ro+c]; s2 += i2[ro+c]; }
  }
  o1[idx] = s1; o2[idx] = s2;
}

// ---- K7d: vertical 17-tap + base_s = boxa*Ys + boxb ----
__global__ __launch_bounds__(256) void k_vbox_fin(const float* __restrict__ h1, const float* __restrict__ h2,
                                                  const float* __restrict__ Ys, float* __restrict__ base){
  int idx = blockIdx.x*256 + threadIdx.x;
  int i = idx >> 11, j = idx & 2047;
  float s1 = 0.f, s2 = 0.f; int ry;
  if (i >= 8 && i < Hh-8){
    #pragma unroll
    for (int d=-8; d<=8; ++d){ int o = ((i+d)<<11) + j; s1 += h1[o]; s2 += h2[o]; }
    ry = 17;
  } else {
    int r0 = max(i-8,0), r1 = min(i+8,Hh-1);
    for (int r=r0; r<=r1; ++r){ int o = (r<<11) + j; s1 += h1[o]; s2 += h2[o]; }
    ry = r1-r0+1;
  }
  int cw = min(j+8, Wh-1) - max(j-8, 0) + 1;
  float inv = 1.0f/(float)(ry*cw);
  base[idx] = fmaf(s1*inv, Ys[idx], s2*inv);
}

// ---- K8: demosaic+CCM (recompute) + LTM + gamma + RGB->YUV -> NV12 ----
__global__ __launch_bounds__(256) void k_final(const float* __restrict__ M, const float* __restrict__ C,
                                               const float* __restrict__ bs, float* __restrict__ out){
  int idx = blockIdx.x*256 + threadIdx.x;
  int i = idx >> 11, j = idx & 2047;
  float m[4][4]; load_m44(M, i, j, m);
  float R[2][2], G[2][2], Bv[2][2];
  demosaic_ccm(m, C, R, G, Bv);

  // bilinear upsample of base_s (half-pixel centers; clamp == jax weight renorm at 2x)
  float bsv[3][3];
  #pragma unroll
  for (int a=0; a<3; ++a){
    int r = min(max(i-1+a, 0), Hh-1);
    #pragma unroll
    for (int b=0; b<3; ++b){
      int c = min(max(j-1+b, 0), Wh-1);
      bsv[a][b] = bs[(r<<11) + c];
    }
  }
  float base[2][2];
  base[0][0] = 0.0625f*bsv[0][0] + 0.1875f*bsv[0][1] + 0.1875f*bsv[1][0] + 0.5625f*bsv[1][1];
  base[0][1] = 0.1875f*bsv[0][1] + 0.0625f*bsv[0][2] + 0.5625f*bsv[1][1] + 0.1875f*bsv[1][2];
  base[1][0] = 0.1875f*bsv[1][0] + 0.5625f*bsv[1][1] + 0.0625f*bsv[2][0] + 0.1875f*bsv[2][1];
  base[1][1] = 0.5625f*bsv[1][1] + 0.1875f*bsv[1][2] + 0.1875f*bsv[2][1] + 0.0625f*bsv[2][2];

  float Yp[2][2];
  float Uacc = 0.f, Vacc = 0.f;
  #pragma unroll
  for (int a=0; a<2; ++a){
    #pragma unroll
    for (int c=0; c<2; ++c){
      float Yl   = 0.299f*R[a][c] + 0.587f*G[a][c] + 0.114f*Bv[a][c];
      float Ynew = fmaf(0.7f, base[a][c], Yl - base[a][c]);   // 0.7*base + (Y-base)
      float sc   = Ynew/(Yl + 1e-6f);
      float Rg = powf(fmaxf(clamp01(R[a][c]*sc),  1e-6f), 1.0f/2.2f);
      float Gg = powf(fmaxf(clamp01(G[a][c]*sc),  1e-6f), 1.0f/2.2f);
      float Bg = powf(fmaxf(clamp01(Bv[a][c]*sc), 1e-6f), 1.0f/2.2f);
      float Yf = 0.299f*Rg + 0.587f*Gg + 0.114f*Bg;
      Yp[a][c] = fminf(fmaxf(Yf*255.0f, 0.0f), 255.0f);
      Uacc += -0.168736f*Rg - 0.331264f*Gg + 0.5f*Bg + 0.5f;
      Vacc +=  0.5f*Rg - 0.418688f*Gg - 0.081312f*Bg + 0.5f;
    }
  }
  *(float2*)(out + (2*i)*IMG_W   + 2*j) = make_float2(Yp[0][0], Yp[0][1]);
  *(float2*)(out + (2*i+1)*IMG_W + 2*j) = make_float2(Yp[1][0], Yp[1][1]);
  float u = fminf(fmaxf(0.25f*Uacc*255.0f, 0.0f), 255.0f);
  float v = fminf(fmaxf(0.25f*Vacc*255.0f, 0.0f), 255.0f);
  *(float2*)(out + IMG_H*IMG_W + i*IMG_W + 2*j) = make_float2(u, v);
}

extern "C" void kernel_launch(void* const* d_in, const int* in_sizes, int n_in,
                              void* d_out, int out_size, void* d_ws, size_t ws_size,
                              hipStream_t stream){
  const float* x   = (const float*)d_in[0];
  const float* ccm = (const float*)d_in[1];
  float* ws  = (float*)d_ws;
  float* out = (float*)d_out;

  // workspace layout (floats), total 12*S + 8 ~= 151 MB:
  //  [0,4S)   P (planes)            -> reused as M (mosaic) after gf2
  //  [4S,5S)  A (gf a, per plane)   -> reused as Ys
  //  [5S,6S)  B (gf b, per plane)   -> reused as h1
  //  [6S,10S) D (denoised planes)   -> reused as h2, Ga, Gb, ha
  //  [10S,11S) hb
  //  [11S,12S) base_s
  //  [12S, +8) sums[4], gains[2]
  size_t need = ((size_t)12*S + 8)*sizeof(float);
  if (ws_size < need) return;  // harness ws too small -> fail loudly via validation

  float* P  = ws;
  float* A  = ws + (size_t)4*S;
  float* B  = ws + (size_t)5*S;
  float* D  = ws + (size_t)6*S;
  float* M  = P;
  float* Ys = A;
  float* h1 = B;
  float* h2 = ws + (size_t)6*S;
  float* Ga = ws + (size_t)7*S;
  float* Gb = ws + (size_t)8*S;
  float* ha = ws + (size_t)9*S;
  float* hb = ws + (size_t)10*S;
  float* bs = ws + (size_t)11*S;
  float* sums  = ws + (size_t)12*S;
  float* gains = sums + 4;

  const int nb = S/256;   // 12288 blocks, exact
  k_split<<<nb, 256, 0, stream>>>(x, P);
  hipMemsetAsync(sums, 0, 4*sizeof(float), stream);
  for (int p = 0; p < 4; ++p){
    k_gf1<<<nb, 256, 0, stream>>>(P + (size_t)p*S, A, B);
    k_gf2<<<nb, 256, 0, stream>>>(P + (size_t)p*S, A, B, D + (size_t)p*S, sums + p);
  }
  k_gains<<<1, 64, 0, stream>>>(sums, gains);
  k_mosaic<<<nb, 256, 0, stream>>>(D, gains, M);
  k_ys<<<nb, 256, 0, stream>>>(M, ccm, Ys);
  k_hbox_sq<<<nb, 256, 0, stream>>>(Ys, h1, h2);
  k_vbox_ab<<<nb, 256, 0, stream>>>(h1, h2, Ga, Gb);
  k_hbox2<<<nb, 256, 0, stream>>>(Ga, Gb, ha, hb);
  k_vbox_fin<<<nb, 256, 0, stream>>>(ha, hb, Ys, bs);
  k_final<<<nb, 256, 0, stream>>>(M, ccm, bs, out);
}

// Round 4
// 467.622 us; speedup vs baseline: 2.3564x; 2.3564x over previous
//
#include <hip/hip_runtime.h>
#include <math.h>

#define IMG_H 3072
#define IMG_W 4096
#define Hh 1536
#define Wh 2048
#define S (Hh*Wh)   // 3,145,728 per-plane pixels

#define TID 8    // rows/thread, denoise box (r=2)
#define TIL 16   // rows/thread, LTM box (r=8)

__device__ __forceinline__ float clamp01(float v){ return fminf(fmaxf(v, 0.0f), 1.0f); }

// jnp.interp over knots (0,0),(0.25,0.5),(1,1) then black-level
__device__ __forceinline__ float decompand_black(float v){
  float y = (v <= 0.25f) ? (2.0f*v) : fmaf(v - 0.25f, 0.5f/0.75f, 0.5f);
  y = clamp01(y);
  return clamp01((y - 0.0625f) * (1.0f/0.9375f));
}

// x^(1/2.2) for x in [1e-6, 1]: v_log_f32 + v_exp_f32 (hardware transcendentals).
// NOTE: __builtin_amdgcn_logf IS log2 (see __clang_hip_math.h __log2f).
__device__ __forceinline__ float gamma22(float x){
  return __builtin_amdgcn_exp2f(0.45454545454545453f * __builtin_amdgcn_logf(x));
}

// ---- K1: decompand + split into 4 RGGB planes ----
__global__ __launch_bounds__(256) void k_split(const float* __restrict__ x, float* __restrict__ P){
  int idx = blockIdx.x*256 + threadIdx.x;
  int i = idx >> 11, j = idx & 2047;
  const float* r0 = x + (2*i)*IMG_W + 2*j;
  const float* r1 = r0 + IMG_W;
  float2 a = *(const float2*)r0;
  float2 b = *(const float2*)r1;
  P[idx]       = decompand_black(a.x);
  P[S + idx]   = decompand_black(a.y);
  P[2*S + idx] = decompand_black(b.x);
  P[3*S + idx] = decompand_black(b.y);
}

// ---- guided-filter pass 1: 2D truncated box of I and I^2 via vertical sliding window ----
// thread = one column j, TI consecutive output rows. Ring buffer of (2R+1) row-sums.
template<int R, int TI>
__global__ __launch_bounds__(256) void k_boxsq_ab(const float* __restrict__ in,
                                                  float* __restrict__ A, float* __restrict__ B,
                                                  float eps){
  int j  = blockIdx.x*256 + threadIdx.x;           // 0..Wh-1
  int i0 = blockIdx.y*TI;
  int cw = min(j+R, Wh-1) - max(j-R, 0) + 1;

  float hs[2*R+1], hs2[2*R+1];
  float ws = 0.f, ws2 = 0.f;
  #pragma unroll
  for (int k=0; k<2*R+1; ++k){
    int r = i0 - R + k;
    float s = 0.f, s2 = 0.f;
    if ((unsigned)r < (unsigned)Hh){
      const float* row = in + r*Wh;
      #pragma unroll
      for (int d=-R; d<=R; ++d){
        int c = j + d;
        float v = ((unsigned)c < (unsigned)Wh) ? row[c] : 0.f;
        s += v; s2 = fmaf(v, v, s2);
      }
    }
    hs[k] = s; hs2[k] = s2; ws += s; ws2 += s2;
  }
  #pragma unroll
  for (int t=0; t<TI; ++t){
    int i = i0 + t;
    int rh = min(i+R, Hh-1) - max(i-R, 0) + 1;
    float inv = 1.0f/(float)(rh*cw);
    float m   = ws*inv;
    float var = fmaf(-m, m, ws2*inv);
    float a   = var/(var + eps);
    A[i*Wh + j] = a;
    B[i*Wh + j] = m*(1.0f - a);
    if (t < TI-1){
      ws -= hs[0]; ws2 -= hs2[0];
      #pragma unroll
      for (int k=0; k<2*R; ++k){ hs[k]=hs[k+1]; hs2[k]=hs2[k+1]; }
      int r = i + R + 1;
      float s = 0.f, s2 = 0.f;
      if (r < Hh){
        const float* row = in + r*Wh;
        #pragma unroll
        for (int d=-R; d<=R; ++d){
          int c = j + d;
          float v = ((unsigned)c < (unsigned)Wh) ? row[c] : 0.f;
          s += v; s2 = fmaf(v, v, s2);
        }
      }
      hs[2*R] = s; hs2[2*R] = s2; ws += s; ws2 += s2;
    }
  }
}

// ---- guided-filter pass 2: 2D box of a and b, D = boxa*I + boxb (+ optional plane sum) ----
template<int R, int TI, bool DOSUM>
__global__ __launch_bounds__(256) void k_box_apply(const float* __restrict__ in,
                                                   const float* __restrict__ A, const float* __restrict__ B,
                                                   float* __restrict__ D, float* __restrict__ sum_out){
  int j  = blockIdx.x*256 + threadIdx.x;
  int i0 = blockIdx.y*TI;
  int cw = min(j+R, Wh-1) - max(j-R, 0) + 1;

  float ha[2*R+1], hb[2*R+1];
  float wa = 0.f, wb = 0.f;
  #pragma unroll
  for (int k=0; k<2*R+1; ++k){
    int r = i0 - R + k;
    float sa = 0.f, sb = 0.f;
    if ((unsigned)r < (unsigned)Hh){
      const float* ra = A + r*Wh;
      const float* rb = B + r*Wh;
      #pragma unroll
      for (int d=-R; d<=R; ++d){
        int c = j + d;
        bool ok = ((unsigned)c < (unsigned)Wh);
        sa += ok ? ra[c] : 0.f;
        sb += ok ? rb[c] : 0.f;
      }
    }
    ha[k] = sa; hb[k] = sb; wa += sa; wb += sb;
  }
  float local = 0.f;
  #pragma unroll
  for (int t=0; t<TI; ++t){
    int i = i0 + t;
    int rh = min(i+R, Hh-1) - max(i-R, 0) + 1;
    float inv = 1.0f/(float)(rh*cw);
    float d = fmaf(wa*inv, in[i*Wh + j], wb*inv);
    D[i*Wh + j] = d;
    if (DOSUM) local += d;
    if (t < TI-1){
      wa -= ha[0]; wb -= hb[0];
      #pragma unroll
      for (int k=0; k<2*R; ++k){ ha[k]=ha[k+1]; hb[k]=hb[k+1]; }
      int r = i + R + 1;
      float sa = 0.f, sb = 0.f;
      if (r < Hh){
        const float* ra = A + r*Wh;
        const float* rb = B + r*Wh;
        #pragma unroll
        for (int d2=-R; d2<=R; ++d2){
          int c = j + d2;
          bool ok = ((unsigned)c < (unsigned)Wh);
          sa += ok ? ra[c] : 0.f;
          sb += ok ? rb[c] : 0.f;
        }
      }
      ha[2*R] = sa; hb[2*R] = sb; wa += sa; wb += sb;
    }
  }
  if (DOSUM){
    __shared__ float red[256];
    red[threadIdx.x] = local;
    __syncthreads();
    #pragma unroll
    for (int off=128; off>0; off>>=1){
      if (threadIdx.x < off) red[threadIdx.x] += red[threadIdx.x+off];
      __syncthreads();
    }
    if (threadIdx.x == 0) atomicAdd(sum_out, red[0]);
  }
}

// ---- AWB gains ----
__global__ void k_gains(const float* __restrict__ sums, float* __restrict__ gains){
  if (threadIdx.x == 0 && blockIdx.x == 0){
    const float inv = 1.0f/(float)S;
    float rm = sums[0]*inv, g1 = sums[1]*inv, g2 = sums[2]*inv, bm = sums[3]*inv;
    float gm = 0.5f*(g1+g2);
    gains[0] = fminf(gm/(rm + 1e-8f), 4.0f);
    gains[1] = fminf(gm/(bm + 1e-8f), 4.0f);
  }
}

// ---- rebuild gained, clipped mosaic ----
__global__ __launch_bounds__(256) void k_mosaic(const float* __restrict__ D, const float* __restrict__ gains,
                                                float* __restrict__ M){
  int idx = blockIdx.x*256 + threadIdx.x;
  int i = idx >> 11, j = idx & 2047;
  float gr = gains[0], gb = gains[1];
  float2 t0 = make_float2(clamp01(D[idx]*gr),  clamp01(D[S+idx]));
  float2 t1 = make_float2(clamp01(D[2*S+idx]), clamp01(D[3*S+idx]*gb));
  *(float2*)(M + (2*i)*IMG_W   + 2*j) = t0;
  *(float2*)(M + (2*i+1)*IMG_W + 2*j) = t1;
}

// ---- shared demosaic helpers (zero-padded 'SAME' 3x3 convs, RGGB) ----
__device__ __forceinline__ void load_m44(const float* __restrict__ M, int i, int j, float m[4][4]){
  int y0 = 2*i - 1, x0 = 2*j - 1;
  #pragma unroll
  for (int a=0; a<4; ++a){
    int yy = y0 + a;
    bool yok = ((unsigned)yy < (unsigned)IMG_H);
    #pragma unroll
    for (int b=0; b<4; ++b){
      int xx = x0 + b;
      m[a][b] = (yok && ((unsigned)xx < (unsigned)IMG_W)) ? M[yy*IMG_W + xx] : 0.0f;
    }
  }
}

__device__ __forceinline__ void demosaic_ccm(const float m[4][4], const float* __restrict__ C,
                                             float R[2][2], float G[2][2], float Bv[2][2]){
  float r[2][2], g[2][2], b[2][2];
  r[0][0] = m[1][1];
  g[0][0] = 0.25f*(m[0][1]+m[2][1]+m[1][0]+m[1][2]);
  b[0][0] = 0.25f*(m[0][0]+m[0][2]+m[2][0]+m[2][2]);
  r[0][1] = 0.5f*(m[1][1]+m[1][3]);
  g[0][1] = m[1][2];
  b[0][1] = 0.5f*(m[0][2]+m[2][2]);
  r[1][0] = 0.5f*(m[1][1]+m[3][1]);
  g[1][0] = m[2][1];
  b[1][0] = 0.5f*(m[2][0]+m[2][2]);
  r[1][1] = 0.25f*(m[1][1]+m[1][3]+m[3][1]+m[3][3]);
  g[1][1] = 0.25f*(m[1][2]+m[3][2]+m[2][1]+m[2][3]);
  b[1][1] = m[2][2];
  #pragma unroll
  for (int a=0; a<2; ++a){
    #pragma unroll
    for (int c=0; c<2; ++c){
      R[a][c]  = clamp01(fmaf(C[2], b[a][c], fmaf(C[1], g[a][c], C[0]*r[a][c])));
      G[a][c]  = clamp01(fmaf(C[5], b[a][c], fmaf(C[4], g[a][c], C[3]*r[a][c])));
      Bv[a][c] = clamp01(fmaf(C[8], b[a][c], fmaf(C[7], g[a][c], C[6]*r[a][c])));
    }
  }
}

// ---- half-res luma Ys ----
__global__ __launch_bounds__(256) void k_ys(const float* __restrict__ M, const float* __restrict__ C,
                                            float* __restrict__ Ys){
  int idx = blockIdx.x*256 + threadIdx.x;
  int i = idx >> 11, j = idx & 2047;
  float m[4][4]; load_m44(M, i, j, m);
  float R[2][2], G[2][2], Bv[2][2];
  demosaic_ccm(m, C, R, G, Bv);
  float y = 0.f;
  #pragma unroll
  for (int a=0; a<2; ++a)
    #pragma unroll
    for (int c=0; c<2; ++c)
      y += 0.299f*R[a][c] + 0.587f*G[a][c] + 0.114f*Bv[a][c];
  Ys[idx] = 0.25f*y;
}

// ---- final: demosaic+CCM (recompute) + LTM + gamma + RGB->YUV -> NV12 ----
__global__ __launch_bounds__(256) void k_final(const float* __restrict__ M, const float* __restrict__ C,
                                               const float* __restrict__ bs, float* __restrict__ out){
  int idx = blockIdx.x*256 + threadIdx.x;
  int i = idx >> 11, j = idx & 2047;
  float m[4][4]; load_m44(M, i, j, m);
  float R[2][2], G[2][2], Bv[2][2];
  demosaic_ccm(m, C, R, G, Bv);

  // bilinear upsample of base_s (half-pixel centers; clamp == jax weight renorm at 2x)
  float bsv[3][3];
  #pragma unroll
  for (int a=0; a<3; ++a){
    int r = min(max(i-1+a, 0), Hh-1);
    #pragma unroll
    for (int b=0; b<3; ++b){
      int c = min(max(j-1+b, 0), Wh-1);
      bsv[a][b] = bs[(r<<11) + c];
    }
  }
  float base[2][2];
  base[0][0] = 0.0625f*bsv[0][0] + 0.1875f*bsv[0][1] + 0.1875f*bsv[1][0] + 0.5625f*bsv[1][1];
  base[0][1] = 0.1875f*bsv[0][1] + 0.0625f*bsv[0][2] + 0.5625f*bsv[1][1] + 0.1875f*bsv[1][2];
  base[1][0] = 0.1875f*bsv[1][0] + 0.5625f*bsv[1][1] + 0.0625f*bsv[2][0] + 0.1875f*bsv[2][1];
  base[1][1] = 0.5625f*bsv[1][1] + 0.1875f*bsv[1][2] + 0.1875f*bsv[2][1] + 0.0625f*bsv[2][2];

  float Yp[2][2];
  float Uacc = 0.f, Vacc = 0.f;
  #pragma unroll
  for (int a=0; a<2; ++a){
    #pragma unroll
    for (int c=0; c<2; ++c){
      float Yl   = 0.299f*R[a][c] + 0.587f*G[a][c] + 0.114f*Bv[a][c];
      float Ynew = fmaf(0.7f, base[a][c], Yl - base[a][c]);
      float sc   = Ynew/(Yl + 1e-6f);
      float Rg = gamma22(fmaxf(clamp01(R[a][c]*sc),  1e-6f));
      float Gg = gamma22(fmaxf(clamp01(G[a][c]*sc),  1e-6f));
      float Bg = gamma22(fmaxf(clamp01(Bv[a][c]*sc), 1e-6f));
      float Yf = 0.299f*Rg + 0.587f*Gg + 0.114f*Bg;
      Yp[a][c] = fminf(fmaxf(Yf*255.0f, 0.0f), 255.0f);
      Uacc += -0.168736f*Rg - 0.331264f*Gg + 0.5f*Bg + 0.5f;
      Vacc +=  0.5f*Rg - 0.418688f*Gg - 0.081312f*Bg + 0.5f;
    }
  }
  *(float2*)(out + (2*i)*IMG_W   + 2*j) = make_float2(Yp[0][0], Yp[0][1]);
  *(float2*)(out + (2*i+1)*IMG_W + 2*j) = make_float2(Yp[1][0], Yp[1][1]);
  float u = fminf(fmaxf(0.25f*Uacc*255.0f, 0.0f), 255.0f);
  float v = fminf(fmaxf(0.25f*Vacc*255.0f, 0.0f), 255.0f);
  *(float2*)(out + IMG_H*IMG_W + i*IMG_W + 2*j) = make_float2(u, v);
}

extern "C" void kernel_launch(void* const* d_in, const int* in_sizes, int n_in,
                              void* d_out, int out_size, void* d_ws, size_t ws_size,
                              hipStream_t stream){
  const float* x   = (const float*)d_in[0];
  const float* ccm = (const float*)d_in[1];
  float* ws  = (float*)d_ws;
  float* out = (float*)d_out;

  // workspace layout (floats), total 10*S + 8 ~= 126 MB:
  //  [0,4S)   P (planes) -> M (mosaic)
  //  [4S,5S)  A (gf a)   -> Ys
  //  [5S,6S)  B (gf b)   -> LTM a
  //  [6S,10S) D (denoised planes); [6S,7S) -> LTM b, [7S,8S) -> base_s
  //  [10S,+8) sums[4], gains[2]
  size_t need = ((size_t)10*S + 8)*sizeof(float);
  if (ws_size < need) return;

  float* P  = ws;
  float* A  = ws + (size_t)4*S;
  float* B  = ws + (size_t)5*S;
  float* D  = ws + (size_t)6*S;
  float* M  = P;
  float* Ys = A;
  float* La = B;
  float* Lb = ws + (size_t)6*S;
  float* bs = ws + (size_t)7*S;
  float* sums  = ws + (size_t)10*S;
  float* gains = sums + 4;

  const int nb = S/256;                     // full 2D index kernels
  dim3 gdn(Wh/256, Hh/TID);                 // denoise box kernels (per plane)
  dim3 gltm(Wh/256, Hh/TIL);                // LTM box kernels

  k_split<<<nb, 256, 0, stream>>>(x, P);
  (void)hipMemsetAsync(sums, 0, 4*sizeof(float), stream);
  for (int p = 0; p < 4; ++p){
    k_boxsq_ab<2, TID><<<gdn, 256, 0, stream>>>(P + (size_t)p*S, A, B, 100.0f);
    k_box_apply<2, TID, true><<<gdn, 256, 0, stream>>>(P + (size_t)p*S, A, B, D + (size_t)p*S, sums + p);
  }
  k_gains<<<1, 64, 0, stream>>>(sums, gains);
  k_mosaic<<<nb, 256, 0, stream>>>(D, gains, M);
  k_ys<<<nb, 256, 0, stream>>>(M, ccm, Ys);
  k_boxsq_ab<8, TIL><<<gltm, 256, 0, stream>>>(Ys, La, Lb, 1e-3f);
  k_box_apply<8, TIL, false><<<gltm, 256, 0, stream>>>(Ys, La, Lb, bs, nullptr);
  k_final<<<nb, 256, 0, stream>>>(M, ccm, bs, out);
}

// Round 5
// 378.829 us; speedup vs baseline: 2.9087x; 1.2344x over previous
//
#include <hip/hip_runtime.h>
#include <math.h>

#define IMG_H 3072
#define IMG_W 4096
#define Hh 1536
#define Wh 2048
#define S (Hh*Wh)   // 3,145,728 per-plane pixels

#define TID 16   // rows/thread, fused denoise
#define TIL 16   // rows/thread, LTM box (r=8)

#if __has_builtin(__builtin_amdgcn_rcpf)
#define RCP(x) __builtin_amdgcn_rcpf(x)
#else
#define RCP(x) (1.0f/(x))
#endif

__device__ __forceinline__ float clamp01(float v){ return fminf(fmaxf(v, 0.0f), 1.0f); }

// jnp.interp over knots (0,0),(0.25,0.5),(1,1) then black-level
__device__ __forceinline__ float decompand_black(float v){
  float y = (v <= 0.25f) ? (2.0f*v) : fmaf(v - 0.25f, 0.5f/0.75f, 0.5f);
  y = clamp01(y);
  return clamp01((y - 0.0625f) * (1.0f/0.9375f));
}

// x^(1/2.2): v_log_f32 + v_exp_f32 (__builtin_amdgcn_logf IS log2)
__device__ __forceinline__ float gamma22(float x){
  return __builtin_amdgcn_exp2f(0.45454545454545453f * __builtin_amdgcn_logf(x));
}

// ---- K1: decompand + split into 4 RGGB planes ----
__global__ __launch_bounds__(256) void k_split(const float* __restrict__ x, float* __restrict__ P){
  int idx = blockIdx.x*256 + threadIdx.x;
  int i = idx >> 11, j = idx & 2047;
  const float* r0 = x + (2*i)*IMG_W + 2*j;
  const float* r1 = r0 + IMG_W;
  float2 a = *(const float2*)r0;
  float2 b = *(const float2*)r1;
  P[idx]       = decompand_black(a.x);
  P[S + idx]   = decompand_black(a.y);
  P[2*S + idx] = decompand_black(b.x);
  P[3*S + idx] = decompand_black(b.y);
}

// ---- fused guided-filter denoise (r=2, eps=100), both box passes in registers ----
// Thread = one column j, TI output rows. Ring buffers:
//   rh1/rh2[5][5]: horizontal 5-sums of I and I^2 for the 5 a-columns, last 5 rows
//   rha/rhb[5]   : horizontal 5-sums of a,b, last 5 rows
//   cI[5]        : center I, last 5 rows (D at ro=r-4 needs I[ro][j])
// Schedule at iteration r: push I-row r; if r>=i0 compute a,b at q=r-2;
// if r>=i0+4 emit D at ro=r-4. Edge truncation: zero loads + analytic counts
// + masks zeroing OOB a-rows/cols.
template<int TI>
__global__ __launch_bounds__(256) void k_denoise(const float* __restrict__ P4,
                                                 float* __restrict__ D4,
                                                 float* __restrict__ sums){
  const int j  = blockIdx.x*256 + threadIdx.x;
  const int i0 = blockIdx.y*TI;
  const int pl = blockIdx.z;
  const float* __restrict__ in = P4 + (size_t)pl*S;
  float* __restrict__ D = D4 + (size_t)pl*S;

  float cw_a[5], amask[5];
  #pragma unroll
  for (int k=0;k<5;++k){
    int pc = j + k - 2;
    bool ok = ((unsigned)pc < (unsigned)Wh);
    amask[k] = ok ? 1.f : 0.f;
    cw_a[k]  = ok ? (float)(min(pc+2, Wh-1) - max(pc-2, 0) + 1) : 1.f;
  }
  const float cw_o = (float)(min(j+2, Wh-1) - max(j-2, 0) + 1);

  float rh1[5][5]={{0}}, rh2[5][5]={{0}};
  float vs1[5]={0}, vs2[5]={0};
  float rha[5]={0}, rhb[5]={0};
  float cI[5]={0};
  float wa=0.f, wb=0.f, local=0.f;

  for (int r=i0-4; r<i0+TI+4; ++r){
    float v[9];
    if ((unsigned)r < (unsigned)Hh){
      const float* rp = in + (size_t)r*Wh;
      #pragma unroll
      for (int d=0; d<9; ++d){
        int c = j + d - 4;
        v[d] = ((unsigned)c < (unsigned)Wh) ? rp[c] : 0.f;
      }
    } else {
      #pragma unroll
      for (int d=0; d<9; ++d) v[d]=0.f;
    }
    float sq[9];
    #pragma unroll
    for (int d=0; d<9; ++d) sq[d]=v[d]*v[d];
    float h1[5], h2[5];
    h1[0]=v[0]+v[1]+v[2]+v[3]+v[4];
    h2[0]=sq[0]+sq[1]+sq[2]+sq[3]+sq[4];
    #pragma unroll
    for (int k=1;k<5;++k){
      h1[k]=h1[k-1]-v[k-1]+v[k+4];
      h2[k]=h2[k-1]-sq[k-1]+sq[k+4];
    }
    #pragma unroll
    for (int k=0;k<5;++k){
      vs1[k]+=h1[k]-rh1[k][0];
      vs2[k]+=h2[k]-rh2[k][0];
      #pragma unroll
      for (int t=0;t<4;++t){ rh1[k][t]=rh1[k][t+1]; rh2[k][t]=rh2[k][t+1]; }
      rh1[k][4]=h1[k]; rh2[k][4]=h2[k];
    }
    #pragma unroll
    for (int t=0;t<4;++t) cI[t]=cI[t+1];
    cI[4]=v[4];

    if (r >= i0){
      int q = r-2;
      float rmask = ((unsigned)q < (unsigned)Hh) ? 1.f : 0.f;
      float rh = (float)(min(q+2, Hh-1) - max(q-2, 0) + 1);
      float ha_=0.f, hb_=0.f;
      #pragma unroll
      for (int k=0;k<5;++k){
        float inv = RCP(rh*cw_a[k]);
        float m   = vs1[k]*inv;
        float var = fmaf(-m, m, vs2[k]*inv);
        float a   = var*RCP(var + 100.0f);
        float b   = m - m*a;
        ha_ = fmaf(a, amask[k], ha_);
        hb_ = fmaf(b, amask[k], hb_);
      }
      ha_ *= rmask; hb_ *= rmask;
      wa += ha_ - rha[0];
      wb += hb_ - rhb[0];
      #pragma unroll
      for (int t=0;t<4;++t){ rha[t]=rha[t+1]; rhb[t]=rhb[t+1]; }
      rha[4]=ha_; rhb[4]=hb_;

      if (r >= i0+4){
        int ro = r-4;
        float rho  = (float)(min(ro+2, Hh-1) - max(ro-2, 0) + 1);
        float invo = RCP(rho*cw_o);
        float d = fmaf(wa*invo, cI[0], wb*invo);
        D[(size_t)ro*Wh + j] = d;
        local += d;
      }
    }
  }

  __shared__ float red[256];
  red[threadIdx.x]=local;
  __syncthreads();
  #pragma unroll
  for (int off=128; off>0; off>>=1){
    if (threadIdx.x<off) red[threadIdx.x]+=red[threadIdx.x+off];
    __syncthreads();
  }
  if (threadIdx.x==0) atomicAdd(sums+pl, red[0]);
}

// ---- LTM box pass 1 (unchanged, r=8) ----
template<int R, int TI>
__global__ __launch_bounds__(256) void k_boxsq_ab(const float* __restrict__ in,
                                                  float* __restrict__ A, float* __restrict__ B,
                                                  float eps){
  int j  = blockIdx.x*256 + threadIdx.x;
  int i0 = blockIdx.y*TI;
  int cw = min(j+R, Wh-1) - max(j-R, 0) + 1;

  float hs[2*R+1], hs2[2*R+1];
  float ws = 0.f, ws2 = 0.f;
  #pragma unroll
  for (int k=0; k<2*R+1; ++k){
    int r = i0 - R + k;
    float s = 0.f, s2 = 0.f;
    if ((unsigned)r < (unsigned)Hh){
      const float* row = in + r*Wh;
      #pragma unroll
      for (int d=-R; d<=R; ++d){
        int c = j + d;
        float v = ((unsigned)c < (unsigned)Wh) ? row[c] : 0.f;
        s += v; s2 = fmaf(v, v, s2);
      }
    }
    hs[k] = s; hs2[k] = s2; ws += s; ws2 += s2;
  }
  #pragma unroll
  for (int t=0; t<TI; ++t){
    int i = i0 + t;
    int rh = min(i+R, Hh-1) - max(i-R, 0) + 1;
    float inv = 1.0f/(float)(rh*cw);
    float m   = ws*inv;
    float var = fmaf(-m, m, ws2*inv);
    float a   = var/(var + eps);
    A[i*Wh + j] = a;
    B[i*Wh + j] = m*(1.0f - a);
    if (t < TI-1){
      ws -= hs[0]; ws2 -= hs2[0];
      #pragma unroll
      for (int k=0; k<2*R; ++k){ hs[k]=hs[k+1]; hs2[k]=hs2[k+1]; }
      int r = i + R + 1;
      float s = 0.f, s2 = 0.f;
      if (r < Hh){
        const float* row = in + r*Wh;
        #pragma unroll
        for (int d=-R; d<=R; ++d){
          int c = j + d;
          float v = ((unsigned)c < (unsigned)Wh) ? row[c] : 0.f;
          s += v; s2 = fmaf(v, v, s2);
        }
      }
      hs[2*R] = s; hs2[2*R] = s2; ws += s; ws2 += s2;
    }
  }
}

// ---- LTM box pass 2 (unchanged, r=8) ----
template<int R, int TI>
__global__ __launch_bounds__(256) void k_box_apply(const float* __restrict__ in,
                                                   const float* __restrict__ A, const float* __restrict__ B,
                                                   float* __restrict__ D){
  int j  = blockIdx.x*256 + threadIdx.x;
  int i0 = blockIdx.y*TI;
  int cw = min(j+R, Wh-1) - max(j-R, 0) + 1;

  float ha[2*R+1], hb[2*R+1];
  float wa = 0.f, wb = 0.f;
  #pragma unroll
  for (int k=0; k<2*R+1; ++k){
    int r = i0 - R + k;
    float sa = 0.f, sb = 0.f;
    if ((unsigned)r < (unsigned)Hh){
      const float* ra = A + r*Wh;
      const float* rb = B + r*Wh;
      #pragma unroll
      for (int d=-R; d<=R; ++d){
        int c = j + d;
        bool ok = ((unsigned)c < (unsigned)Wh);
        sa += ok ? ra[c] : 0.f;
        sb += ok ? rb[c] : 0.f;
      }
    }
    ha[k] = sa; hb[k] = sb; wa += sa; wb += sb;
  }
  #pragma unroll
  for (int t=0; t<TI; ++t){
    int i = i0 + t;
    int rh = min(i+R, Hh-1) - max(i-R, 0) + 1;
    float inv = 1.0f/(float)(rh*cw);
    D[i*Wh + j] = fmaf(wa*inv, in[i*Wh + j], wb*inv);
    if (t < TI-1){
      wa -= ha[0]; wb -= hb[0];
      #pragma unroll
      for (int k=0; k<2*R; ++k){ ha[k]=ha[k+1]; hb[k]=hb[k+1]; }
      int r = i + R + 1;
      float sa = 0.f, sb = 0.f;
      if (r < Hh){
        const float* ra = A + r*Wh;
        const float* rb = B + r*Wh;
        #pragma unroll
        for (int d2=-R; d2<=R; ++d2){
          int c = j + d2;
          bool ok = ((unsigned)c < (unsigned)Wh);
          sa += ok ? ra[c] : 0.f;
          sb += ok ? rb[c] : 0.f;
        }
      }
      ha[2*R] = sa; hb[2*R] = sb; wa += sa; wb += sb;
    }
  }
}

// ---- AWB gains ----
__global__ void k_gains(const float* __restrict__ sums, float* __restrict__ gains){
  if (threadIdx.x == 0 && blockIdx.x == 0){
    const float inv = 1.0f/(float)S;
    float rm = sums[0]*inv, g1 = sums[1]*inv, g2 = sums[2]*inv, bm = sums[3]*inv;
    float gm = 0.5f*(g1+g2);
    gains[0] = fminf(gm/(rm + 1e-8f), 4.0f);
    gains[1] = fminf(gm/(bm + 1e-8f), 4.0f);
  }
}

// ---- rebuild gained, clipped mosaic ----
__global__ __launch_bounds__(256) void k_mosaic(const float* __restrict__ D, const float* __restrict__ gains,
                                                float* __restrict__ M){
  int idx = blockIdx.x*256 + threadIdx.x;
  int i = idx >> 11, j = idx & 2047;
  float gr = gains[0], gb = gains[1];
  float2 t0 = make_float2(clamp01(D[idx]*gr),  clamp01(D[S+idx]));
  float2 t1 = make_float2(clamp01(D[2*S+idx]), clamp01(D[3*S+idx]*gb));
  *(float2*)(M + (2*i)*IMG_W   + 2*j) = t0;
  *(float2*)(M + (2*i+1)*IMG_W + 2*j) = t1;
}

// ---- shared demosaic helpers (zero-padded 'SAME' 3x3 convs, RGGB) ----
__device__ __forceinline__ void load_m44(const float* __restrict__ M, int i, int j, float m[4][4]){
  int y0 = 2*i - 1, x0 = 2*j - 1;
  #pragma unroll
  for (int a=0; a<4; ++a){
    int yy = y0 + a;
    bool yok = ((unsigned)yy < (unsigned)IMG_H);
    #pragma unroll
    for (int b=0; b<4; ++b){
      int xx = x0 + b;
      m[a][b] = (yok && ((unsigned)xx < (unsigned)IMG_W)) ? M[yy*IMG_W + xx] : 0.0f;
    }
  }
}

__device__ __forceinline__ void demosaic_ccm(const float m[4][4], const float* __restrict__ C,
                                             float R[2][2], float G[2][2], float Bv[2][2]){
  float r[2][2], g[2][2], b[2][2];
  r[0][0] = m[1][1];
  g[0][0] = 0.25f*(m[0][1]+m[2][1]+m[1][0]+m[1][2]);
  b[0][0] = 0.25f*(m[0][0]+m[0][2]+m[2][0]+m[2][2]);
  r[0][1] = 0.5f*(m[1][1]+m[1][3]);
  g[0][1] = m[1][2];
  b[0][1] = 0.5f*(m[0][2]+m[2][2]);
  r[1][0] = 0.5f*(m[1][1]+m[3][1]);
  g[1][0] = m[2][1];
  b[1][0] = 0.5f*(m[2][0]+m[2][2]);
  r[1][1] = 0.25f*(m[1][1]+m[1][3]+m[3][1]+m[3][3]);
  g[1][1] = 0.25f*(m[1][2]+m[3][2]+m[2][1]+m[2][3]);
  b[1][1] = m[2][2];
  #pragma unroll
  for (int a=0; a<2; ++a){
    #pragma unroll
    for (int c=0; c<2; ++c){
      R[a][c]  = clamp01(fmaf(C[2], b[a][c], fmaf(C[1], g[a][c], C[0]*r[a][c])));
      G[a][c]  = clamp01(fmaf(C[5], b[a][c], fmaf(C[4], g[a][c], C[3]*r[a][c])));
      Bv[a][c] = clamp01(fmaf(C[8], b[a][c], fmaf(C[7], g[a][c], C[6]*r[a][c])));
    }
  }
}

// ---- half-res luma Ys ----
__global__ __launch_bounds__(256) void k_ys(const float* __restrict__ M, const float* __restrict__ C,
                                            float* __restrict__ Ys){
  int idx = blockIdx.x*256 + threadIdx.x;
  int i = idx >> 11, j = idx & 2047;
  float m[4][4]; load_m44(M, i, j, m);
  float R[2][2], G[2][2], Bv[2][2];
  demosaic_ccm(m, C, R, G, Bv);
  float y = 0.f;
  #pragma unroll
  for (int a=0; a<2; ++a)
    #pragma unroll
    for (int c=0; c<2; ++c)
      y += 0.299f*R[a][c] + 0.587f*G[a][c] + 0.114f*Bv[a][c];
  Ys[idx] = 0.25f*y;
}

// ---- final: demosaic+CCM (recompute) + LTM + gamma + RGB->YUV -> NV12 ----
__global__ __launch_bounds__(256) void k_final(const float* __restrict__ M, const float* __restrict__ C,
                                               const float* __restrict__ bs, float* __restrict__ out){
  int idx = blockIdx.x*256 + threadIdx.x;
  int i = idx >> 11, j = idx & 2047;
  float m[4][4]; load_m44(M, i, j, m);
  float R[2][2], G[2][2], Bv[2][2];
  demosaic_ccm(m, C, R, G, Bv);

  float bsv[3][3];
  #pragma unroll
  for (int a=0; a<3; ++a){
    int r = min(max(i-1+a, 0), Hh-1);
    #pragma unroll
    for (int b=0; b<3; ++b){
      int c = min(max(j-1+b, 0), Wh-1);
      bsv[a][b] = bs[(r<<11) + c];
    }
  }
  float base[2][2];
  base[0][0] = 0.0625f*bsv[0][0] + 0.1875f*bsv[0][1] + 0.1875f*bsv[1][0] + 0.5625f*bsv[1][1];
  base[0][1] = 0.1875f*bsv[0][1] + 0.0625f*bsv[0][2] + 0.5625f*bsv[1][1] + 0.1875f*bsv[1][2];
  base[1][0] = 0.1875f*bsv[1][0] + 0.5625f*bsv[1][1] + 0.0625f*bsv[2][0] + 0.1875f*bsv[2][1];
  base[1][1] = 0.5625f*bsv[1][1] + 0.1875f*bsv[1][2] + 0.1875f*bsv[2][1] + 0.0625f*bsv[2][2];

  float Yp[2][2];
  float Uacc = 0.f, Vacc = 0.f;
  #pragma unroll
  for (int a=0; a<2; ++a){
    #pragma unroll
    for (int c=0; c<2; ++c){
      float Yl   = 0.299f*R[a][c] + 0.587f*G[a][c] + 0.114f*Bv[a][c];
      float Ynew = fmaf(0.7f, base[a][c], Yl - base[a][c]);
      float sc   = Ynew/(Yl + 1e-6f);
      float Rg = gamma22(fmaxf(clamp01(R[a][c]*sc),  1e-6f));
      float Gg = gamma22(fmaxf(clamp01(G[a][c]*sc),  1e-6f));
      float Bg = gamma22(fmaxf(clamp01(Bv[a][c]*sc), 1e-6f));
      float Yf = 0.299f*Rg + 0.587f*Gg + 0.114f*Bg;
      Yp[a][c] = fminf(fmaxf(Yf*255.0f, 0.0f), 255.0f);
      Uacc += -0.168736f*Rg - 0.331264f*Gg + 0.5f*Bg + 0.5f;
      Vacc +=  0.5f*Rg - 0.418688f*Gg - 0.081312f*Bg + 0.5f;
    }
  }
  *(float2*)(out + (2*i)*IMG_W   + 2*j) = make_float2(Yp[0][0], Yp[0][1]);
  *(float2*)(out + (2*i+1)*IMG_W + 2*j) = make_float2(Yp[1][0], Yp[1][1]);
  float u = fminf(fmaxf(0.25f*Uacc*255.0f, 0.0f), 255.0f);
  float v = fminf(fmaxf(0.25f*Vacc*255.0f, 0.0f), 255.0f);
  *(float2*)(out + IMG_H*IMG_W + i*IMG_W + 2*j) = make_float2(u, v);
}

extern "C" void kernel_launch(void* const* d_in, const int* in_sizes, int n_in,
                              void* d_out, int out_size, void* d_ws, size_t ws_size,
                              hipStream_t stream){
  const float* x   = (const float*)d_in[0];
  const float* ccm = (const float*)d_in[1];
  float* ws  = (float*)d_ws;
  float* out = (float*)d_out;

  // workspace layout (floats), total 10*S + 8:
  //  [0,4S)   P (planes) -> M (mosaic)
  //  [4S,8S)  D (denoised planes); after k_mosaic: [4S,5S) -> LTM b, [5S,6S) -> base_s
  //  [8S,9S)  Ys
  //  [9S,10S) LTM a
  //  [10S,+8) sums[4], gains[2]
  size_t need = ((size_t)10*S + 8)*sizeof(float);
  if (ws_size < need) return;

  float* P  = ws;
  float* D  = ws + (size_t)4*S;
  float* Ys = ws + (size_t)8*S;
  float* La = ws + (size_t)9*S;
  float* Lb = ws + (size_t)4*S;
  float* bs = ws + (size_t)5*S;
  float* M  = P;
  float* sums  = ws + (size_t)10*S;
  float* gains = sums + 4;

  const int nb = S/256;
  dim3 gdn(Wh/256, Hh/TID, 4);              // fused denoise, all planes
  dim3 gltm(Wh/256, Hh/TIL);                // LTM box kernels

  k_split<<<nb, 256, 0, stream>>>(x, P);
  (void)hipMemsetAsync(sums, 0, 4*sizeof(float), stream);
  k_denoise<TID><<<gdn, 256, 0, stream>>>(P, D, sums);
  k_gains<<<1, 64, 0, stream>>>(sums, gains);
  k_mosaic<<<nb, 256, 0, stream>>>(D, gains, M);
  k_ys<<<nb, 256, 0, stream>>>(M, ccm, Ys);
  k_boxsq_ab<8, TIL><<<gltm, 256, 0, stream>>>(Ys, La, Lb, 1e-3f);
  k_box_apply<8, TIL><<<gltm, 256, 0, stream>>>(Ys, La, Lb, bs);
  k_final<<<nb, 256, 0, stream>>>(M, ccm, bs, out);
}